// Round 1
// baseline (378.262 us; speedup 1.0000x reference)
//
#include <hip/hip_runtime.h>

// Swin window attention, fully fused: roll -> QKV (bf16 MFMA) -> windowed
// attention (bf16 MFMA, fp32 softmax) -> out-proj (bf16 MFMA) -> roll back.
//
// R3 change: persistent per-window-position blocks. grid 4096 -> 256; each
// block owns one (wh,ww) window position and loops over the 16 batches.
// Rationale (R2 = 350.5us, ~22us per serialized block-slot vs ~4us of static
// work): with 108.5KB LDS -> 1 block/CU, 4096 blocks execute as 16 strictly
// serial slots per CU, each re-paying cold-start latency (x window, weights,
// pe/masks, bias build) plus a full end-of-block drain. Persistent loop:
//   - bias table built ONCE (window position fixed -> mask variant fixed)
//   - wqkvT/woutT/pe stay L1-hot across 16 iterations
//   - next batch's x window prefetched into registers during QKV/QK^T phases
//     and written to LDS during softmax (T14 async-stage split)
//   - out-proj stores of batch b overlap QKV GEMM of batch b+1 (no barrier
//     between phase 5 and next phase 1; the phase-1-end barrier orders LDS)
//   - phase 1 rebalanced: 48 half-tiles over 16 waves = 3 tasks each
//     (was 24 tiles = 2-vs-1 imbalance)
// 4 barriers per batch iteration; xs single-buffered (written in phase 3,
// two barriers after its last read in phase 1).
//
// MFMA 16x16x32 bf16 fragment layouts (HW-verified per guide m89/m91/m120):
//   A[m][k]: m = lane&15, k = (lane>>4)*8 + j   (8 contiguous bf16 = 16B)
//   B[k][n]: n = lane&15, k = (lane>>4)*8 + j
//   D[m][n]: n = lane&15, m = (lane>>4)*4 + reg

typedef __bf16 bf16x8 __attribute__((ext_vector_type(8)));
typedef short  s16x8  __attribute__((ext_vector_type(8)));
typedef float  f32x4  __attribute__((ext_vector_type(4)));

static __device__ __forceinline__ float bf2f(unsigned short u) {
  unsigned x = ((unsigned)u) << 16;
  return __builtin_bit_cast(float, x);
}
static __device__ __forceinline__ unsigned short f2bf(float f) {
  unsigned x = __builtin_bit_cast(unsigned, f);
  x += 0x7FFFu + ((x >> 16) & 1u);   // round-to-nearest-even
  return (unsigned short)(x >> 16);
}
static __device__ __forceinline__ f32x4 mfma16(s16x8 a, s16x8 b, f32x4 c) {
  return __builtin_amdgcn_mfma_f32_16x16x32_bf16(
      __builtin_bit_cast(bf16x8, a), __builtin_bit_cast(bf16x8, b), c, 0, 0, 0);
}

// ---------------- prep: transpose + bf16-cast weights into workspace --------
__global__ void prep_weights(const float* __restrict__ wqkv,
                             const float* __restrict__ wout,
                             unsigned short* __restrict__ wqkvT,
                             unsigned short* __restrict__ woutT) {
  int idx = blockIdx.x * blockDim.x + threadIdx.x;
  const int total1 = 384 * 128;
  if (idx < total1) {
    int n = idx >> 7, k = idx & 127;
    wqkvT[idx] = f2bf(wqkv[k * 384 + n]);
  } else {
    int i2 = idx - total1;
    int n = i2 >> 7, k = i2 & 127;
    woutT[i2] = f2bf(wout[k * 128 + n]);
  }
}

// ---------------- fused main kernel -----------------------------------------
// LDS regions (bytes), no unions (persistent pipeline keeps all live):
//   xs   [64][136] bf16   17408  @ 0        (staged x window, batch-cycled)
//   q    [64][136] bf16   17408  @ 17408
//   k    [64][136] bf16   17408  @ 34816
//   v    [128][72] bf16   18432  @ 52224    (v transposed: [ch][tok])
//   S    [4][64][72] bf16 36864  @ 70656
//   oa   [64][136] bf16   17408  @ 107520   (attention output, pre-proj)
//   bias [64][65] f32     16640  @ 124928   (built once per block)
//   rsum [4][64] f32       1024  @ 141568
#define OFF_XS  0
#define OFF_Q   17408
#define OFF_K   34816
#define OFF_V   52224
#define OFF_S   70656
#define OFF_OA  107520
#define OFF_BI  124928
#define OFF_RS  141568
#define SMEM_SZ 142592

#define BATCH_STRIDE (128 * 128 * 128)   // floats per batch image

__global__ __launch_bounds__(1024, 4)
void swin_fused(const float* __restrict__ x,
                const unsigned short* __restrict__ wqkvT,
                const unsigned short* __restrict__ woutT,
                const float* __restrict__ b_out,
                const float* __restrict__ pe,     // [15][15]
                const float* __restrict__ ulm,    // [64][64]
                const float* __restrict__ lrm,    // [64][64]
                float* __restrict__ out) {
  __shared__ __align__(16) unsigned char smem[SMEM_SZ];
  unsigned short* xs_s   = (unsigned short*)(smem + OFF_XS);
  unsigned short* q_s    = (unsigned short*)(smem + OFF_Q);
  unsigned short* k_s    = (unsigned short*)(smem + OFF_K);
  unsigned short* v_s    = (unsigned short*)(smem + OFF_V);
  unsigned short* S_s    = (unsigned short*)(smem + OFF_S);
  unsigned short* oa_s   = (unsigned short*)(smem + OFF_OA);
  float*          bias_s = (float*)(smem + OFF_BI);
  float*          rsum_s = (float*)(smem + OFF_RS);

  const int tid  = threadIdx.x;
  const int lane = tid & 63;
  const int wave = tid >> 6;       // 0..15
  const int ln15 = lane & 15;
  const int quad = lane >> 4;
  const int m_sub = quad << 2;

  const int wh = blockIdx.x >> 4, ww = blockIdx.x & 15;

  // per-thread x-staging addresses: 2 float4 chunks/thread, constant across
  // batches (only the batch base advances).
  const int tokA = tid >> 5, c4 = tid & 31;    // 32 float4 per 128-ch token row
  const int tokB = tokA + 32;                  // (tid+1024)>>5 == tokA+32
  const int giA = ((wh << 3) + (tokA >> 3) + 4) & 127;
  const int gjA = ((ww << 3) + (tokA & 7) + 4) & 127;
  const int giB = ((wh << 3) + (tokB >> 3) + 4) & 127;
  const int gjB = ((ww << 3) + (tokB & 7) + 4) & 127;
  const float* xA = x + ((giA * 128 + gjA) * 128 + c4 * 4);
  const float* xB = x + ((giB * 128 + gjB) * 128 + c4 * 4);

  // ---- prologue: stage batch-0 x window + build bias table (once) ----
  {
    float4 a0 = *(const float4*)xA;
    float4 b0 = *(const float4*)xB;
    ushort4 pk;
    pk.x = f2bf(a0.x); pk.y = f2bf(a0.y); pk.z = f2bf(a0.z); pk.w = f2bf(a0.w);
    *(ushort4*)(xs_s + tokA * 136 + c4 * 4) = pk;
    pk.x = f2bf(b0.x); pk.y = f2bf(b0.y); pk.z = f2bf(b0.z); pk.w = f2bf(b0.w);
    *(ushort4*)(xs_s + tokB * 136 + c4 * 4) = pk;

    const bool has_ul = (wh == 15), has_lr = (ww == 15);
#pragma unroll
    for (int it = 0; it < 4; ++it) {
      int t = tid + it * 1024;             // 4096 bias entries
      int i = t >> 6, j = t & 63;
      int r0 = (j >> 3) - (i >> 3) + 7;
      int r1 = (j & 7) - (i & 7) + 7;
      float bsum = pe[r0 * 15 + r1];
      if (has_ul) bsum += ulm[t];
      if (has_lr) bsum += lrm[t];
      bias_s[i * 65 + j] = bsum;
    }
  }
  __syncthreads();

  for (int b = 0; b < 16; ++b) {
    // ---- phase 1: QKV GEMM (M=64,K=128,N=384) + prefetch issue ----------
    // Prefetch next batch's x window into registers; consumed in phase 3.
    float4 pfA, pfB;
    const bool pf = (b < 15);
    if (pf) {
      pfA = *(const float4*)(xA + (b + 1) * BATCH_STRIDE);
      pfB = *(const float4*)(xB + (b + 1) * BATCH_STRIDE);
    }
    // 48 half-tiles (24 n-tiles x 2 m-halves) over 16 waves = 3 tasks each.
    for (int it = 0; it < 3; ++it) {
      int t  = wave + (it << 4);
      int nt = t >> 1, mh = t & 1;
      int n0 = nt << 4;
      int n  = n0 + ln15;
      const unsigned short* wp = wqkvT + n * 128 + quad * 8;
      s16x8 bfr[4];
#pragma unroll
      for (int ks = 0; ks < 4; ++ks) bfr[ks] = *(const s16x8*)(wp + ks * 32);
#pragma unroll
      for (int mi = 0; mi < 2; ++mi) {
        int mt = mh * 2 + mi;
        f32x4 acc = {0.f, 0.f, 0.f, 0.f};
#pragma unroll
        for (int ks = 0; ks < 4; ++ks) {
          s16x8 a = *(const s16x8*)(xs_s + (mt * 16 + ln15) * 136 + ks * 32 + quad * 8);
          acc = mfma16(a, bfr[ks], acc);
        }
        int tok0 = mt * 16 + m_sub;
        if (n0 < 128) {               // q
#pragma unroll
          for (int r = 0; r < 4; ++r) q_s[(tok0 + r) * 136 + n] = f2bf(acc[r]);
        } else if (n0 < 256) {        // k
          int nn = n - 128;
#pragma unroll
          for (int r = 0; r < 4; ++r) k_s[(tok0 + r) * 136 + nn] = f2bf(acc[r]);
        } else {                      // v (transposed [ch][tok])
          int nn = n - 256;
          ushort4 pk;
          pk.x = f2bf(acc[0]); pk.y = f2bf(acc[1]);
          pk.z = f2bf(acc[2]); pk.w = f2bf(acc[3]);
          *(ushort4*)(v_s + nn * 72 + tok0) = pk;
        }
      }
    }
    __syncthreads();

    // ---- phase 2: QK^T * scale + bias -> S; task = (head, m-tile) --------
    {
      const int h  = wave >> 2;
      const int mt = wave & 3;
      unsigned short* Sh = S_s + h * 64 * 72;
      s16x8 qf = *(const s16x8*)(q_s + (mt * 16 + ln15) * 136 + h * 32 + quad * 8);
      const float scale = 0.17677669529663687f;   // 32^-0.5
#pragma unroll
      for (int nt = 0; nt < 4; ++nt) {
        s16x8 kf = *(const s16x8*)(k_s + (nt * 16 + ln15) * 136 + h * 32 + quad * 8);
        f32x4 acc = {0.f, 0.f, 0.f, 0.f};
        acc = mfma16(qf, kf, acc);
        int nn = nt * 16 + ln15;
        int tok0 = mt * 16 + m_sub;
#pragma unroll
        for (int r = 0; r < 4; ++r) {
          float sv = acc[r] * scale + bias_s[(tok0 + r) * 65 + nn];
          Sh[(tok0 + r) * 72 + nn] = f2bf(sv);
        }
      }
    }
    __syncthreads();

    // ---- phase 3: write prefetched xs (next batch), then softmax ---------
    // xs last read in phase 1 (two barriers ago) -> safe to overwrite here;
    // ds_write latency overlaps the softmax VALU work below.
    if (pf) {
      ushort4 pk;
      pk.x = f2bf(pfA.x); pk.y = f2bf(pfA.y); pk.z = f2bf(pfA.z); pk.w = f2bf(pfA.w);
      *(ushort4*)(xs_s + tokA * 136 + c4 * 4) = pk;
      pk.x = f2bf(pfB.x); pk.y = f2bf(pfB.y); pk.z = f2bf(pfB.z); pk.w = f2bf(pfB.w);
      *(ushort4*)(xs_s + tokB * 136 + c4 * 4) = pk;
    }
    {
      const int h   = wave >> 2;
      const int row = (wave & 3) * 16 + ln15;
      unsigned short* rp = S_s + h * 64 * 72 + row * 72 + quad * 16;
      float vals[16];
      float mx = -1e30f;
#pragma unroll
      for (int c = 0; c < 2; ++c) {
        s16x8 s8 = *(const s16x8*)(rp + c * 8);
#pragma unroll
        for (int j = 0; j < 8; ++j) {
          float f = bf2f((unsigned short)s8[j]);
          vals[c * 8 + j] = f;
          mx = fmaxf(mx, f);
        }
      }
      mx = fmaxf(mx, __shfl_xor(mx, 16));
      mx = fmaxf(mx, __shfl_xor(mx, 32));
      float sum = 0.f;
#pragma unroll
      for (int c = 0; c < 2; ++c) {
        s16x8 st;
#pragma unroll
        for (int j = 0; j < 8; ++j) {
          float e = __expf(vals[c * 8 + j] - mx);
          sum += e;
          st[j] = (short)f2bf(e);
        }
        *(s16x8*)(rp + c * 8) = st;
      }
      sum += __shfl_xor(sum, 16);
      sum += __shfl_xor(sum, 32);
      if (quad == 0) rsum_s[h * 64 + row] = 1.0f / sum;
    }
    __syncthreads();

    // ---- phase 4: PV (M=64,K=64,N=32); task = (head, m-tile) -------------
    {
      const int h  = wave >> 2;
      const int mt = wave & 3;
      unsigned short* Sh = S_s + h * 64 * 72;
      s16x8 pfr[2];
#pragma unroll
      for (int ks = 0; ks < 2; ++ks)
        pfr[ks] = *(const s16x8*)(Sh + (mt * 16 + ln15) * 72 + ks * 32 + quad * 8);
      int tok0 = mt * 16 + m_sub;
      float rc[4];
#pragma unroll
      for (int r = 0; r < 4; ++r) rc[r] = rsum_s[h * 64 + tok0 + r];
#pragma unroll
      for (int nt = 0; nt < 2; ++nt) {
        f32x4 acc = {0.f, 0.f, 0.f, 0.f};
#pragma unroll
        for (int ks = 0; ks < 2; ++ks) {
          s16x8 vf = *(const s16x8*)(v_s + (h * 32 + nt * 16 + ln15) * 72 + ks * 32 + quad * 8);
          acc = mfma16(pfr[ks], vf, acc);
        }
        int n = h * 32 + nt * 16 + ln15;
#pragma unroll
        for (int r = 0; r < 4; ++r)
          oa_s[(tok0 + r) * 136 + n] = f2bf(acc[r] * rc[r]);
      }
    }
    __syncthreads();

    // ---- phase 5: out proj (M=64,K=128,N=128); stores overlap next ph1 ---
    // No barrier after this phase: it reads oa/woutT and writes global only;
    // next iteration's phase 1 touches xs/q/k/v. The phase-1-end barrier
    // orders phase 5 against the next S/oa writers.
    {
      const int nt  = wave >> 1;           // 0..7
      const int mtb = (wave & 1) * 2;      // {0,2}
      int n = nt * 16 + ln15;
      s16x8 bfr[4];
      const unsigned short* wp = woutT + n * 128 + quad * 8;
#pragma unroll
      for (int ks = 0; ks < 4; ++ks) bfr[ks] = *(const s16x8*)(wp + ks * 32);
      float bo = b_out[n];
      float* outb = out + b * BATCH_STRIDE;
#pragma unroll
      for (int mi = 0; mi < 2; ++mi) {
        int mt = mtb + mi;
        f32x4 acc = {0.f, 0.f, 0.f, 0.f};
#pragma unroll
        for (int ks = 0; ks < 4; ++ks) {
          s16x8 a = *(const s16x8*)(oa_s + (mt * 16 + ln15) * 136 + ks * 32 + quad * 8);
          acc = mfma16(a, bfr[ks], acc);
        }
        int tok0 = mt * 16 + m_sub;
#pragma unroll
        for (int r = 0; r < 4; ++r) {
          int tok = tok0 + r;
          int ti = tok >> 3, tj = tok & 7;
          int gi = (wh * 8 + ti + 4) & 127;
          int gj = (ww * 8 + tj + 4) & 127;
          outb[(gi * 128 + gj) * 128 + n] = acc[r] + bo;
        }
      }
    }
  }
}

extern "C" void kernel_launch(void* const* d_in, const int* in_sizes, int n_in,
                              void* d_out, int out_size, void* d_ws, size_t ws_size,
                              hipStream_t stream) {
  const float* x    = (const float*)d_in[0];
  const float* wqkv = (const float*)d_in[1];
  const float* wout = (const float*)d_in[2];
  const float* bout = (const float*)d_in[3];
  const float* pe   = (const float*)d_in[4];
  const float* ulm  = (const float*)d_in[5];
  const float* lrm  = (const float*)d_in[6];

  unsigned short* wqkvT = (unsigned short*)d_ws;           // 384*128 bf16
  unsigned short* woutT = wqkvT + 384 * 128;               // 128*128 bf16

  prep_weights<<<(384 * 128 + 128 * 128) / 256, 256, 0, stream>>>(wqkv, wout, wqkvT, woutT);
  swin_fused<<<256, 1024, 0, stream>>>(x, wqkvT, woutT, bout, pe, ulm, lrm,
                                       (float*)d_out);
}

// Round 2
// 376.637 us; speedup vs baseline: 1.0043x; 1.0043x over previous
//
#include <hip/hip_runtime.h>

// Swin window attention, fully fused: roll -> QKV (bf16 MFMA) -> windowed
// attention (bf16 MFMA, fp32 register softmax) -> out-proj (bf16 MFMA) -> roll.
//
// R4 changes (from R3 @ 213.9us kernel, MfmaUtil 8%, VALUBusy 19%, HBM 30%
// -- latency-bound, 13.4us/iter vs ~4us of work):
//  1. QK^T + softmax + PV fused into ONE phase. Softmax is done in registers
//     on the QK^T D-fragments (row = mt*16+quad*4+r is constant across the
//     16 ln15-lanes of a quad -> row-reduce = 3 in-lane ops + shfl_xor
//     1/2/4/8). P is normalized in-register and stored to LDS ONCE; the PV
//     A-fragment read-back is same-wave only (wave (h,mt) writes and reads
//     exactly rows [mt*16, mt*16+16) of head h), so a wave-level
//     s_waitcnt lgkmcnt(0) replaces two full block barriers.
//     Barriers: 4/iter -> 2/iter. rsum buffer + phase-3 eliminated.
//  2. QKV weight fragments (12 x s16x8 = 48 VGPR) hoisted out of the batch
//     loop -- each wave's 3 (nt,mh) tasks are identical every iteration, so
//     the 12 L2 loads (~250cy each) repaid 16x are now paid once.
// Phase structure per batch: [P1 QKV] bar [P2 attn fused + xs prefetch-write]
// bar [P5 out-proj, no barrier -> next P1 overlaps stores].
//
// MFMA 16x16x32 bf16 fragment layouts (HW-verified per guide m89/m91/m120):
//   A[m][k]: m = lane&15, k = (lane>>4)*8 + j   (8 contiguous bf16 = 16B)
//   B[k][n]: n = lane&15, k = (lane>>4)*8 + j
//   D[m][n]: n = lane&15, m = (lane>>4)*4 + reg

typedef __bf16 bf16x8 __attribute__((ext_vector_type(8)));
typedef short  s16x8  __attribute__((ext_vector_type(8)));
typedef float  f32x4  __attribute__((ext_vector_type(4)));

static __device__ __forceinline__ float bf2f(unsigned short u) {
  unsigned x = ((unsigned)u) << 16;
  return __builtin_bit_cast(float, x);
}
static __device__ __forceinline__ unsigned short f2bf(float f) {
  unsigned x = __builtin_bit_cast(unsigned, f);
  x += 0x7FFFu + ((x >> 16) & 1u);   // round-to-nearest-even
  return (unsigned short)(x >> 16);
}
static __device__ __forceinline__ f32x4 mfma16(s16x8 a, s16x8 b, f32x4 c) {
  return __builtin_amdgcn_mfma_f32_16x16x32_bf16(
      __builtin_bit_cast(bf16x8, a), __builtin_bit_cast(bf16x8, b), c, 0, 0, 0);
}

// ---------------- prep: transpose + bf16-cast weights into workspace --------
__global__ void prep_weights(const float* __restrict__ wqkv,
                             const float* __restrict__ wout,
                             unsigned short* __restrict__ wqkvT,
                             unsigned short* __restrict__ woutT) {
  int idx = blockIdx.x * blockDim.x + threadIdx.x;
  const int total1 = 384 * 128;
  if (idx < total1) {
    int n = idx >> 7, k = idx & 127;
    wqkvT[idx] = f2bf(wqkv[k * 384 + n]);
  } else {
    int i2 = idx - total1;
    int n = i2 >> 7, k = i2 & 127;
    woutT[i2] = f2bf(wout[k * 128 + n]);
  }
}

// ---------------- fused main kernel -----------------------------------------
// LDS regions (bytes):
//   xs   [64][136] bf16   17408  @ 0        (staged x window, batch-cycled)
//   q    [64][136] bf16   17408  @ 17408
//   k    [64][136] bf16   17408  @ 34816
//   v    [128][72] bf16   18432  @ 52224    (v transposed: [ch][tok])
//   S    [4][64][72] bf16 36864  @ 70656    (normalized P, wave-private rows)
//   oa   [64][136] bf16   17408  @ 107520   (attention output, pre-proj)
//   bias [64][65] f32     16640  @ 124928   (built once per block)
#define OFF_XS  0
#define OFF_Q   17408
#define OFF_K   34816
#define OFF_V   52224
#define OFF_S   70656
#define OFF_OA  107520
#define OFF_BI  124928
#define SMEM_SZ 141568

#define BATCH_STRIDE (128 * 128 * 128)   // floats per batch image

__global__ __launch_bounds__(1024, 4)
void swin_fused(const float* __restrict__ x,
                const unsigned short* __restrict__ wqkvT,
                const unsigned short* __restrict__ woutT,
                const float* __restrict__ b_out,
                const float* __restrict__ pe,     // [15][15]
                const float* __restrict__ ulm,    // [64][64]
                const float* __restrict__ lrm,    // [64][64]
                float* __restrict__ out) {
  __shared__ __align__(16) unsigned char smem[SMEM_SZ];
  unsigned short* xs_s   = (unsigned short*)(smem + OFF_XS);
  unsigned short* q_s    = (unsigned short*)(smem + OFF_Q);
  unsigned short* k_s    = (unsigned short*)(smem + OFF_K);
  unsigned short* v_s    = (unsigned short*)(smem + OFF_V);
  unsigned short* S_s    = (unsigned short*)(smem + OFF_S);
  unsigned short* oa_s   = (unsigned short*)(smem + OFF_OA);
  float*          bias_s = (float*)(smem + OFF_BI);

  const int tid  = threadIdx.x;
  const int lane = tid & 63;
  const int wave = tid >> 6;       // 0..15
  const int ln15 = lane & 15;
  const int quad = lane >> 4;
  const int m_sub = quad << 2;

  const int wh = blockIdx.x >> 4, ww = blockIdx.x & 15;

  // per-thread x-staging addresses: 2 float4 chunks/thread, constant across
  // batches (only the batch base advances).
  const int tokA = tid >> 5, c4 = tid & 31;    // 32 float4 per 128-ch token row
  const int tokB = tokA + 32;
  const int giA = ((wh << 3) + (tokA >> 3) + 4) & 127;
  const int gjA = ((ww << 3) + (tokA & 7) + 4) & 127;
  const int giB = ((wh << 3) + (tokB >> 3) + 4) & 127;
  const int gjB = ((ww << 3) + (tokB & 7) + 4) & 127;
  const float* xA = x + ((giA * 128 + gjA) * 128 + c4 * 4);
  const float* xB = x + ((giB * 128 + gjB) * 128 + c4 * 4);

  // ---- hoisted QKV weight fragments: 3 tasks x 4 k-slices = 48 VGPR ----
  s16x8 wf[3][4];
#pragma unroll
  for (int it = 0; it < 3; ++it) {
    int t  = wave + (it << 4);
    int nt = t >> 1;
    int n  = (nt << 4) + ln15;
    const unsigned short* wp = wqkvT + n * 128 + quad * 8;
#pragma unroll
    for (int ks = 0; ks < 4; ++ks) wf[it][ks] = *(const s16x8*)(wp + ks * 32);
  }

  // ---- prologue: stage batch-0 x window + build bias table (once) ----
  {
    float4 a0 = *(const float4*)xA;
    float4 b0 = *(const float4*)xB;
    ushort4 pk;
    pk.x = f2bf(a0.x); pk.y = f2bf(a0.y); pk.z = f2bf(a0.z); pk.w = f2bf(a0.w);
    *(ushort4*)(xs_s + tokA * 136 + c4 * 4) = pk;
    pk.x = f2bf(b0.x); pk.y = f2bf(b0.y); pk.z = f2bf(b0.z); pk.w = f2bf(b0.w);
    *(ushort4*)(xs_s + tokB * 136 + c4 * 4) = pk;

    const bool has_ul = (wh == 15), has_lr = (ww == 15);
#pragma unroll
    for (int it = 0; it < 4; ++it) {
      int t = tid + it * 1024;             // 4096 bias entries
      int i = t >> 6, j = t & 63;
      int r0 = (j >> 3) - (i >> 3) + 7;
      int r1 = (j & 7) - (i & 7) + 7;
      float bsum = pe[r0 * 15 + r1];
      if (has_ul) bsum += ulm[t];
      if (has_lr) bsum += lrm[t];
      bias_s[i * 65 + j] = bsum;
    }
  }
  __syncthreads();

  for (int b = 0; b < 16; ++b) {
    // ---- phase 1: QKV GEMM (M=64,K=128,N=384) + prefetch issue ----------
    float4 pfA, pfB;
    const bool pf = (b < 15);
    if (pf) {
      pfA = *(const float4*)(xA + (b + 1) * BATCH_STRIDE);
      pfB = *(const float4*)(xB + (b + 1) * BATCH_STRIDE);
    }
    // 48 half-tiles (24 n-tiles x 2 m-halves) over 16 waves = 3 tasks each.
#pragma unroll
    for (int it = 0; it < 3; ++it) {
      int t  = wave + (it << 4);
      int nt = t >> 1, mh = t & 1;
      int n0 = nt << 4;
      int n  = n0 + ln15;
#pragma unroll
      for (int mi = 0; mi < 2; ++mi) {
        int mt = mh * 2 + mi;
        f32x4 acc = {0.f, 0.f, 0.f, 0.f};
#pragma unroll
        for (int ks = 0; ks < 4; ++ks) {
          s16x8 a = *(const s16x8*)(xs_s + (mt * 16 + ln15) * 136 + ks * 32 + quad * 8);
          acc = mfma16(a, wf[it][ks], acc);
        }
        int tok0 = mt * 16 + m_sub;
        if (n0 < 128) {               // q
#pragma unroll
          for (int r = 0; r < 4; ++r) q_s[(tok0 + r) * 136 + n] = f2bf(acc[r]);
        } else if (n0 < 256) {        // k
          int nn = n - 128;
#pragma unroll
          for (int r = 0; r < 4; ++r) k_s[(tok0 + r) * 136 + nn] = f2bf(acc[r]);
        } else {                      // v (transposed [ch][tok])
          int nn = n - 256;
          ushort4 pk;
          pk.x = f2bf(acc[0]); pk.y = f2bf(acc[1]);
          pk.z = f2bf(acc[2]); pk.w = f2bf(acc[3]);
          *(ushort4*)(v_s + nn * 72 + tok0) = pk;
        }
      }
    }
    __syncthreads();

    // ---- phase 2 (fused): QK^T + bias -> register softmax -> P -> PV -----
    {
      const int h  = wave >> 2;
      const int mt = wave & 3;
      unsigned short* Sh = S_s + h * 64 * 72;
      const int tok0 = mt * 16 + m_sub;
      s16x8 qf = *(const s16x8*)(q_s + (mt * 16 + ln15) * 136 + h * 32 + quad * 8);
      const float scale = 0.17677669529663687f;   // 32^-0.5
      f32x4 sv[4];
#pragma unroll
      for (int nt = 0; nt < 4; ++nt) {
        s16x8 kf = *(const s16x8*)(k_s + (nt * 16 + ln15) * 136 + h * 32 + quad * 8);
        f32x4 acc = {0.f, 0.f, 0.f, 0.f};
        acc = mfma16(qf, kf, acc);
        int nn = nt * 16 + ln15;
#pragma unroll
        for (int r = 0; r < 4; ++r)
          sv[nt][r] = acc[r] * scale + bias_s[(tok0 + r) * 65 + nn];
      }

      // write next batch's prefetched x window (xs dead since phase-1 bar;
      // ds_write latency overlaps the softmax VALU below)
      if (pf) {
        ushort4 pk;
        pk.x = f2bf(pfA.x); pk.y = f2bf(pfA.y); pk.z = f2bf(pfA.z); pk.w = f2bf(pfA.w);
        *(ushort4*)(xs_s + tokA * 136 + c4 * 4) = pk;
        pk.x = f2bf(pfB.x); pk.y = f2bf(pfB.y); pk.z = f2bf(pfB.z); pk.w = f2bf(pfB.w);
        *(ushort4*)(xs_s + tokB * 136 + c4 * 4) = pk;
      }

      // register softmax: row tok0+r is shared by the 16 ln15-lanes of this
      // quad; cols per lane = {nt*16+ln15}. Reduce: in-lane over nt, then
      // shfl_xor 1/2/4/8 (stays within the 16-lane ln15 group).
      float rinv[4];
#pragma unroll
      for (int r = 0; r < 4; ++r) {
        float m0 = fmaxf(fmaxf(sv[0][r], sv[1][r]), fmaxf(sv[2][r], sv[3][r]));
        m0 = fmaxf(m0, __shfl_xor(m0, 1));
        m0 = fmaxf(m0, __shfl_xor(m0, 2));
        m0 = fmaxf(m0, __shfl_xor(m0, 4));
        m0 = fmaxf(m0, __shfl_xor(m0, 8));
        float s0 = 0.f;
#pragma unroll
        for (int nt = 0; nt < 4; ++nt) {
          float e = __expf(sv[nt][r] - m0);
          sv[nt][r] = e;
          s0 += e;
        }
        s0 += __shfl_xor(s0, 1);
        s0 += __shfl_xor(s0, 2);
        s0 += __shfl_xor(s0, 4);
        s0 += __shfl_xor(s0, 8);
        rinv[r] = 1.0f / s0;
      }
      // store normalized P (bf16) -- only rows [mt*16, mt*16+16) of head h,
      // read back below by THIS wave only.
#pragma unroll
      for (int nt = 0; nt < 4; ++nt) {
        int nn = nt * 16 + ln15;
#pragma unroll
        for (int r = 0; r < 4; ++r)
          Sh[(tok0 + r) * 72 + nn] = f2bf(sv[nt][r] * rinv[r]);
      }
      // same-wave LDS RAW: wave-level drain, no block barrier needed
      asm volatile("s_waitcnt lgkmcnt(0)" ::: "memory");
      __builtin_amdgcn_sched_barrier(0);

      // PV (M=64,K=64,N=32 for this head)
      s16x8 pfr[2];
#pragma unroll
      for (int ks = 0; ks < 2; ++ks)
        pfr[ks] = *(const s16x8*)(Sh + (mt * 16 + ln15) * 72 + ks * 32 + quad * 8);
#pragma unroll
      for (int nt = 0; nt < 2; ++nt) {
        f32x4 acc = {0.f, 0.f, 0.f, 0.f};
#pragma unroll
        for (int ks = 0; ks < 2; ++ks) {
          s16x8 vf = *(const s16x8*)(v_s + (h * 32 + nt * 16 + ln15) * 72 + ks * 32 + quad * 8);
          acc = mfma16(pfr[ks], vf, acc);
        }
        int n = h * 32 + nt * 16 + ln15;
#pragma unroll
        for (int r = 0; r < 4; ++r)
          oa_s[(tok0 + r) * 136 + n] = f2bf(acc[r]);
      }
    }
    __syncthreads();

    // ---- phase 5: out proj (M=64,K=128,N=128); stores overlap next ph1 ---
    // No barrier after this phase: it reads oa/woutT and writes global only;
    // next iteration's phase 1 touches xs/q/k/v, ordered by its own barrier.
    {
      const int nt  = wave >> 1;           // 0..7
      const int mtb = (wave & 1) * 2;      // {0,2}
      int n = nt * 16 + ln15;
      s16x8 bfr[4];
      const unsigned short* wp = woutT + n * 128 + quad * 8;
#pragma unroll
      for (int ks = 0; ks < 4; ++ks) bfr[ks] = *(const s16x8*)(wp + ks * 32);
      float bo = b_out[n];
      float* outb = out + b * BATCH_STRIDE;
#pragma unroll
      for (int mi = 0; mi < 2; ++mi) {
        int mt = mtb + mi;
        f32x4 acc = {0.f, 0.f, 0.f, 0.f};
#pragma unroll
        for (int ks = 0; ks < 4; ++ks) {
          s16x8 a = *(const s16x8*)(oa_s + (mt * 16 + ln15) * 136 + ks * 32 + quad * 8);
          acc = mfma16(a, bfr[ks], acc);
        }
        int tok0 = mt * 16 + m_sub;
#pragma unroll
        for (int r = 0; r < 4; ++r) {
          int tok = tok0 + r;
          int ti = tok >> 3, tj = tok & 7;
          int gi = (wh * 8 + ti + 4) & 127;
          int gj = (ww * 8 + tj + 4) & 127;
          outb[(gi * 128 + gj) * 128 + n] = acc[r] + bo;
        }
      }
    }
  }
}

extern "C" void kernel_launch(void* const* d_in, const int* in_sizes, int n_in,
                              void* d_out, int out_size, void* d_ws, size_t ws_size,
                              hipStream_t stream) {
  const float* x    = (const float*)d_in[0];
  const float* wqkv = (const float*)d_in[1];
  const float* wout = (const float*)d_in[2];
  const float* bout = (const float*)d_in[3];
  const float* pe   = (const float*)d_in[4];
  const float* ulm  = (const float*)d_in[5];
  const float* lrm  = (const float*)d_in[6];

  unsigned short* wqkvT = (unsigned short*)d_ws;           // 384*128 bf16
  unsigned short* woutT = wqkvT + 384 * 128;               // 128*128 bf16

  prep_weights<<<(384 * 128 + 128 * 128) / 256, 256, 0, stream>>>(wqkv, wout, wqkvT, woutT);
  swin_fused<<<256, 1024, 0, stream>>>(x, wqkvT, woutT, bout, pe, ulm, lrm,
                                       (float*)d_out);
}

// Round 5
// 320.758 us; speedup vs baseline: 1.1793x; 1.1742x over previous
//
#include <hip/hip_runtime.h>

// Swin window attention, fully fused: roll -> QKV (bf16 MFMA) -> windowed
// attention (bf16 MFMA, fp32 register softmax) -> out-proj (bf16 MFMA) -> roll.
//
// R5 changes (from R4 @ 216.4us, MfmaUtil 8%, VALUBusy 21%, hbm 400MB vs
// 268MB compulsory -- excess = write-allocate RMW fetch on scattered 4B/lane
// out stores; and every __syncthreads drains vmcnt(0), serializing store
// retirement into the per-iteration critical path):
//  1. Full-line out writes: phase 5 stages f32 results to LDS (S region is
//     dead after phase 2; [64][132] f32 = 33.8KB fits in S's 36.9KB), then a
//     coalesced store pass writes 512B-contiguous token rows as float4 --
//     every 128B line fully covered, no read-for-ownership.
//  2. Raw barriers (sched_barrier + s_waitcnt lgkmcnt(0) + s_barrier) inside
//     the batch loop -- no vmcnt(0) drain anywhere in the loop, so global
//     stores and x-prefetch loads stay in flight across barriers. Cross-wave
//     LDS hazards all covered: q/k/v (ph1->ph2: bar), P same-wave (lgkmcnt),
//     oa (ph2->ph5: bar), osr (ph5->ph6: bar; ph6->next ph5: ph1/ph2-end
//     bars), xs (ph2 write -> next ph1 read: ph2-end bar + ph1-end bar).
// (2nd resubmission: two consecutive GPUAcquisitionTimeouts -- this source
// has never executed; keeping it unchanged preserves attribution.)
//
// MFMA 16x16x32 bf16 fragment layouts (HW-verified per guide m89/m91/m120):
//   A[m][k]: m = lane&15, k = (lane>>4)*8 + j   (8 contiguous bf16 = 16B)
//   B[k][n]: n = lane&15, k = (lane>>4)*8 + j
//   D[m][n]: n = lane&15, m = (lane>>4)*4 + reg

typedef __bf16 bf16x8 __attribute__((ext_vector_type(8)));
typedef short  s16x8  __attribute__((ext_vector_type(8)));
typedef float  f32x4  __attribute__((ext_vector_type(4)));

static __device__ __forceinline__ float bf2f(unsigned short u) {
  unsigned x = ((unsigned)u) << 16;
  return __builtin_bit_cast(float, x);
}
static __device__ __forceinline__ unsigned short f2bf(float f) {
  unsigned x = __builtin_bit_cast(unsigned, f);
  x += 0x7FFFu + ((x >> 16) & 1u);   // round-to-nearest-even
  return (unsigned short)(x >> 16);
}
static __device__ __forceinline__ f32x4 mfma16(s16x8 a, s16x8 b, f32x4 c) {
  return __builtin_amdgcn_mfma_f32_16x16x32_bf16(
      __builtin_bit_cast(bf16x8, a), __builtin_bit_cast(bf16x8, b), c, 0, 0, 0);
}
// LDS-only barrier: orders ds ops across waves without draining vmcnt, so
// in-flight global stores/loads are NOT serialized into the barrier.
static __device__ __forceinline__ void bar_lds() {
  __builtin_amdgcn_sched_barrier(0);
  asm volatile("s_waitcnt lgkmcnt(0)" ::: "memory");
  __builtin_amdgcn_s_barrier();
  __builtin_amdgcn_sched_barrier(0);
}

// ---------------- prep: transpose + bf16-cast weights into workspace --------
__global__ void prep_weights(const float* __restrict__ wqkv,
                             const float* __restrict__ wout,
                             unsigned short* __restrict__ wqkvT,
                             unsigned short* __restrict__ woutT) {
  int idx = blockIdx.x * blockDim.x + threadIdx.x;
  const int total1 = 384 * 128;
  if (idx < total1) {
    int n = idx >> 7, k = idx & 127;
    wqkvT[idx] = f2bf(wqkv[k * 384 + n]);
  } else {
    int i2 = idx - total1;
    int n = i2 >> 7, k = i2 & 127;
    woutT[i2] = f2bf(wout[k * 128 + n]);
  }
}

// ---------------- fused main kernel -----------------------------------------
// LDS regions (bytes):
//   xs   [64][136] bf16   17408  @ 0        (staged x window, batch-cycled)
//   q    [64][136] bf16   17408  @ 17408
//   k    [64][136] bf16   17408  @ 34816
//   v    [128][72] bf16   18432  @ 52224    (v transposed: [ch][tok])
//   S    [4][64][72] bf16 36864  @ 70656    (P in ph2; f32 osr[64][132] in ph5/6)
//   oa   [64][136] bf16   17408  @ 107520   (attention output, pre-proj)
//   bias [64][65] f32     16640  @ 124928   (built once per block)
#define OFF_XS  0
#define OFF_Q   17408
#define OFF_K   34816
#define OFF_V   52224
#define OFF_S   70656
#define OFF_OA  107520
#define OFF_BI  124928
#define SMEM_SZ 141568

#define BATCH_STRIDE (128 * 128 * 128)   // floats per batch image

__global__ __launch_bounds__(1024, 4)
void swin_fused(const float* __restrict__ x,
                const unsigned short* __restrict__ wqkvT,
                const unsigned short* __restrict__ woutT,
                const float* __restrict__ b_out,
                const float* __restrict__ pe,     // [15][15]
                const float* __restrict__ ulm,    // [64][64]
                const float* __restrict__ lrm,    // [64][64]
                float* __restrict__ out) {
  __shared__ __align__(16) unsigned char smem[SMEM_SZ];
  unsigned short* xs_s   = (unsigned short*)(smem + OFF_XS);
  unsigned short* q_s    = (unsigned short*)(smem + OFF_Q);
  unsigned short* k_s    = (unsigned short*)(smem + OFF_K);
  unsigned short* v_s    = (unsigned short*)(smem + OFF_V);
  unsigned short* S_s    = (unsigned short*)(smem + OFF_S);
  float*          osr_s  = (float*)(smem + OFF_S);          // union with S
  unsigned short* oa_s   = (unsigned short*)(smem + OFF_OA);
  float*          bias_s = (float*)(smem + OFF_BI);

  const int tid  = threadIdx.x;
  const int lane = tid & 63;
  const int wave = tid >> 6;       // 0..15
  const int ln15 = lane & 15;
  const int quad = lane >> 4;
  const int m_sub = quad << 2;

  const int wh = blockIdx.x >> 4, ww = blockIdx.x & 15;

  // per-thread x/out addresses: 2 token-quarter-rows per thread, constant
  // across batches (only the batch base advances).
  const int tokA = tid >> 5, c4 = tid & 31;    // 32 float4 per 128-ch token row
  const int tokB = tokA + 32;
  const int giA = ((wh << 3) + (tokA >> 3) + 4) & 127;
  const int gjA = ((ww << 3) + (tokA & 7) + 4) & 127;
  const int giB = ((wh << 3) + (tokB >> 3) + 4) & 127;
  const int gjB = ((ww << 3) + (tokB & 7) + 4) & 127;
  const long offA = (long)(giA * 128 + gjA) * 128 + c4 * 4;
  const long offB = (long)(giB * 128 + gjB) * 128 + c4 * 4;
  const float* xA = x + offA;
  const float* xB = x + offB;

  // ---- prologue: stage batch-0 x window + build bias table (once) ----
  {
    float4 a0 = *(const float4*)xA;
    float4 b0 = *(const float4*)xB;
    ushort4 pk;
    pk.x = f2bf(a0.x); pk.y = f2bf(a0.y); pk.z = f2bf(a0.z); pk.w = f2bf(a0.w);
    *(ushort4*)(xs_s + tokA * 136 + c4 * 4) = pk;
    pk.x = f2bf(b0.x); pk.y = f2bf(b0.y); pk.z = f2bf(b0.z); pk.w = f2bf(b0.w);
    *(ushort4*)(xs_s + tokB * 136 + c4 * 4) = pk;

    const bool has_ul = (wh == 15), has_lr = (ww == 15);
#pragma unroll
    for (int it = 0; it < 4; ++it) {
      int t = tid + it * 1024;             // 4096 bias entries
      int i = t >> 6, j = t & 63;
      int r0 = (j >> 3) - (i >> 3) + 7;
      int r1 = (j & 7) - (i & 7) + 7;
      float bsum = pe[r0 * 15 + r1];
      if (has_ul) bsum += ulm[t];
      if (has_lr) bsum += lrm[t];
      bias_s[i * 65 + j] = bsum;
    }
  }
  __syncthreads();

  for (int b = 0; b < 16; ++b) {
    // ---- phase 1: QKV GEMM (M=64,K=128,N=384) + prefetch issue ----------
    float4 pfA, pfB;
    const bool pf = (b < 15);
    if (pf) {
      pfA = *(const float4*)(xA + (b + 1) * BATCH_STRIDE);
      pfB = *(const float4*)(xB + (b + 1) * BATCH_STRIDE);
    }
    // 48 half-tiles (24 n-tiles x 2 m-halves) over 16 waves = 3 tasks each.
#pragma unroll
    for (int it = 0; it < 3; ++it) {
      int t  = wave + (it << 4);
      int nt = t >> 1, mh = t & 1;
      int n0 = nt << 4;
      int n  = n0 + ln15;
      const unsigned short* wp = wqkvT + n * 128 + quad * 8;
      s16x8 bfr[4];
#pragma unroll
      for (int ks = 0; ks < 4; ++ks) bfr[ks] = *(const s16x8*)(wp + ks * 32);
#pragma unroll
      for (int mi = 0; mi < 2; ++mi) {
        int mt = mh * 2 + mi;
        f32x4 acc = {0.f, 0.f, 0.f, 0.f};
#pragma unroll
        for (int ks = 0; ks < 4; ++ks) {
          s16x8 a = *(const s16x8*)(xs_s + (mt * 16 + ln15) * 136 + ks * 32 + quad * 8);
          acc = mfma16(a, bfr[ks], acc);
        }
        int tok0 = mt * 16 + m_sub;
        if (n0 < 128) {               // q
#pragma unroll
          for (int r = 0; r < 4; ++r) q_s[(tok0 + r) * 136 + n] = f2bf(acc[r]);
        } else if (n0 < 256) {        // k
          int nn = n - 128;
#pragma unroll
          for (int r = 0; r < 4; ++r) k_s[(tok0 + r) * 136 + nn] = f2bf(acc[r]);
        } else {                      // v (transposed [ch][tok])
          int nn = n - 256;
          ushort4 pk;
          pk.x = f2bf(acc[0]); pk.y = f2bf(acc[1]);
          pk.z = f2bf(acc[2]); pk.w = f2bf(acc[3]);
          *(ushort4*)(v_s + nn * 72 + tok0) = pk;
        }
      }
    }
    bar_lds();

    // ---- phase 2 (fused): QK^T + bias -> register softmax -> P -> PV -----
    {
      const int h  = wave >> 2;
      const int mt = wave & 3;
      unsigned short* Sh = S_s + h * 64 * 72;
      const int tok0 = mt * 16 + m_sub;
      s16x8 qf = *(const s16x8*)(q_s + (mt * 16 + ln15) * 136 + h * 32 + quad * 8);
      const float scale = 0.17677669529663687f;   // 32^-0.5
      f32x4 sv[4];
#pragma unroll
      for (int nt = 0; nt < 4; ++nt) {
        s16x8 kf = *(const s16x8*)(k_s + (nt * 16 + ln15) * 136 + h * 32 + quad * 8);
        f32x4 acc = {0.f, 0.f, 0.f, 0.f};
        acc = mfma16(qf, kf, acc);
        int nn = nt * 16 + ln15;
#pragma unroll
        for (int r = 0; r < 4; ++r)
          sv[nt][r] = acc[r] * scale + bias_s[(tok0 + r) * 65 + nn];
      }

      // write next batch's prefetched x window (xs dead since ph1-end bar;
      // compiler inserts the vmcnt wait for pfA/pfB right before use)
      if (pf) {
        ushort4 pk;
        pk.x = f2bf(pfA.x); pk.y = f2bf(pfA.y); pk.z = f2bf(pfA.z); pk.w = f2bf(pfA.w);
        *(ushort4*)(xs_s + tokA * 136 + c4 * 4) = pk;
        pk.x = f2bf(pfB.x); pk.y = f2bf(pfB.y); pk.z = f2bf(pfB.z); pk.w = f2bf(pfB.w);
        *(ushort4*)(xs_s + tokB * 136 + c4 * 4) = pk;
      }

      // register softmax: row tok0+r is shared by the 16 ln15-lanes of this
      // quad; cols per lane = {nt*16+ln15}. Reduce: in-lane over nt, then
      // shfl_xor 1/2/4/8 (stays within the 16-lane ln15 group).
      float rinv[4];
#pragma unroll
      for (int r = 0; r < 4; ++r) {
        float m0 = fmaxf(fmaxf(sv[0][r], sv[1][r]), fmaxf(sv[2][r], sv[3][r]));
        m0 = fmaxf(m0, __shfl_xor(m0, 1));
        m0 = fmaxf(m0, __shfl_xor(m0, 2));
        m0 = fmaxf(m0, __shfl_xor(m0, 4));
        m0 = fmaxf(m0, __shfl_xor(m0, 8));
        float s0 = 0.f;
#pragma unroll
        for (int nt = 0; nt < 4; ++nt) {
          float e = __expf(sv[nt][r] - m0);
          sv[nt][r] = e;
          s0 += e;
        }
        s0 += __shfl_xor(s0, 1);
        s0 += __shfl_xor(s0, 2);
        s0 += __shfl_xor(s0, 4);
        s0 += __shfl_xor(s0, 8);
        rinv[r] = 1.0f / s0;
      }
      // store normalized P (bf16) -- only rows [mt*16, mt*16+16) of head h,
      // read back below by THIS wave only.
#pragma unroll
      for (int nt = 0; nt < 4; ++nt) {
        int nn = nt * 16 + ln15;
#pragma unroll
        for (int r = 0; r < 4; ++r)
          Sh[(tok0 + r) * 72 + nn] = f2bf(sv[nt][r] * rinv[r]);
      }
      // same-wave LDS RAW: wave-level drain, no block barrier needed
      asm volatile("s_waitcnt lgkmcnt(0)" ::: "memory");
      __builtin_amdgcn_sched_barrier(0);

      // PV (M=64,K=64,N=32 for this head)
      s16x8 pfr[2];
#pragma unroll
      for (int ks = 0; ks < 2; ++ks)
        pfr[ks] = *(const s16x8*)(Sh + (mt * 16 + ln15) * 72 + ks * 32 + quad * 8);
#pragma unroll
      for (int nt = 0; nt < 2; ++nt) {
        f32x4 acc = {0.f, 0.f, 0.f, 0.f};
#pragma unroll
        for (int ks = 0; ks < 2; ++ks) {
          s16x8 vf = *(const s16x8*)(v_s + (h * 32 + nt * 16 + ln15) * 72 + ks * 32 + quad * 8);
          acc = mfma16(pfr[ks], vf, acc);
        }
        int n = h * 32 + nt * 16 + ln15;
#pragma unroll
        for (int r = 0; r < 4; ++r)
          oa_s[(tok0 + r) * 136 + n] = f2bf(acc[r]);
      }
    }
    bar_lds();

    // ---- phase 5: out proj (M=64,K=128,N=128) -> stage f32 rows to LDS ---
    {
      const int nt  = wave >> 1;           // 0..7
      const int mtb = (wave & 1) * 2;      // {0,2}
      int n = nt * 16 + ln15;
      s16x8 bfr[4];
      const unsigned short* wp = woutT + n * 128 + quad * 8;
#pragma unroll
      for (int ks = 0; ks < 4; ++ks) bfr[ks] = *(const s16x8*)(wp + ks * 32);
      float bo = b_out[n];
#pragma unroll
      for (int mi = 0; mi < 2; ++mi) {
        int mt = mtb + mi;
        f32x4 acc = {0.f, 0.f, 0.f, 0.f};
#pragma unroll
        for (int ks = 0; ks < 4; ++ks) {
          s16x8 a = *(const s16x8*)(oa_s + (mt * 16 + ln15) * 136 + ks * 32 + quad * 8);
          acc = mfma16(a, bfr[ks], acc);
        }
        int tok0 = mt * 16 + m_sub;
#pragma unroll
        for (int r = 0; r < 4; ++r)
          osr_s[(tok0 + r) * 132 + n] = acc[r] + bo;
      }
    }
    bar_lds();

    // ---- phase 6: coalesced store -- full 512B token rows as float4 ------
    // Each 128B out-line fully covered by one wave-instruction: no
    // write-allocate RMW fetch, fast store retirement (never drained by a
    // barrier anyway -- bar_lds leaves vmcnt alone).
    {
      float* outb = out + b * BATCH_STRIDE;
      float4 o0 = *(const float4*)(osr_s + tokA * 132 + c4 * 4);
      *(float4*)(outb + offA) = o0;
      float4 o1 = *(const float4*)(osr_s + tokB * 132 + c4 * 4);
      *(float4*)(outb + offB) = o1;
    }
    // no barrier here: next ph1 touches xs/q/k/v (disjoint from osr); the
    // ph1-end barrier orders these ds_reads against next ph2's S writes.
  }
}

extern "C" void kernel_launch(void* const* d_in, const int* in_sizes, int n_in,
                              void* d_out, int out_size, void* d_ws, size_t ws_size,
                              hipStream_t stream) {
  const float* x    = (const float*)d_in[0];
  const float* wqkv = (const float*)d_in[1];
  const float* wout = (const float*)d_in[2];
  const float* bout = (const float*)d_in[3];
  const float* pe   = (const float*)d_in[4];
  const float* ulm  = (const float*)d_in[5];
  const float* lrm  = (const float*)d_in[6];

  unsigned short* wqkvT = (unsigned short*)d_ws;           // 384*128 bf16
  unsigned short* woutT = wqkvT + 384 * 128;               // 128*128 bf16

  prep_weights<<<(384 * 128 + 128 * 128) / 256, 256, 0, stream>>>(wqkv, wout, wqkvT, woutT);
  swin_fused<<<256, 1024, 0, stream>>>(x, wqkvT, woutT, bout, pe, ulm, lrm,
                                       (float*)d_out);
}